// Round 1
// baseline (466.643 us; speedup 1.0000x reference)
//
#include <hip/hip_runtime.h>
#include <math.h>

// Problem constants (fixed by the reference)
#define Bc   4
#define Tt   2048
#define HIDc 1024
#define NHc  16
#define HSc  64
#define BTc  (Bc * Tt)          // 8192
#define QSCALE 0.18033688011112042f   // 0.125 * log2(e): folded into q so exp(s/8)=2^acc

typedef __attribute__((ext_vector_type(8))) short bf16x8;   // 8 bf16 = 4 VGPRs
typedef __attribute__((ext_vector_type(4))) float f32x4;

__device__ __forceinline__ unsigned short f2bf(float f) {
    unsigned u = __float_as_uint(f);
    u = u + 0x7FFFu + ((u >> 16) & 1u);   // round-to-nearest-even
    return (unsigned short)(u >> 16);
}

__device__ __forceinline__ float fexp2(float x) {
#if __has_builtin(__builtin_amdgcn_exp2f)
    return __builtin_amdgcn_exp2f(x);
#else
    float r; asm("v_exp_f32 %0, %1" : "=v"(r) : "v"(x)); return r;
#endif
}

// ---------------------------------------------------------------------------
// fp32 GEMM (Wo epilogue): C = (A + A2) @ B + bias, 64x64 tile.
// A2 (optional) is the second split-K partial from gemm_pv.
// ---------------------------------------------------------------------------
__global__ __launch_bounds__(256) void gemm_f32(
    const float* __restrict__ A, const float* __restrict__ A2,
    const float* __restrict__ Bm, const float* __restrict__ bias,
    float* __restrict__ C, int M, int N, int K)
{
    __shared__ float As[16][64];
    __shared__ float Bs[16][64];

    const int tid  = threadIdx.x;
    const int tx   = tid & 15;
    const int ty   = tid >> 4;
    const int row0 = blockIdx.y * 64;
    const int col0 = blockIdx.x * 64;

    const int la_r = tid >> 2;
    const int la_c = (tid & 3) << 2;
    const int lb_r = tid >> 4;
    const int lb_c = (tid & 15) << 2;

    float acc[4][4] = {};

    for (int k0 = 0; k0 < K; k0 += 16) {
        float4 av = *(const float4*)&A[(long)(row0 + la_r) * K + k0 + la_c];
        if (A2) {
            float4 a2 = *(const float4*)&A2[(long)(row0 + la_r) * K + k0 + la_c];
            av.x += a2.x; av.y += a2.y; av.z += a2.z; av.w += a2.w;
        }
        float4 bv = *(const float4*)&Bm[(long)(k0 + lb_r) * N + col0 + lb_c];
        __syncthreads();
        As[la_c + 0][la_r] = av.x;
        As[la_c + 1][la_r] = av.y;
        As[la_c + 2][la_r] = av.z;
        As[la_c + 3][la_r] = av.w;
        *(float4*)&Bs[lb_r][lb_c] = bv;
        __syncthreads();
#pragma unroll
        for (int kk = 0; kk < 16; ++kk) {
            float4 a = *(float4*)&As[kk][ty << 2];
            float4 b = *(float4*)&Bs[kk][tx << 2];
            float ar[4] = {a.x, a.y, a.z, a.w};
            float br[4] = {b.x, b.y, b.z, b.w};
#pragma unroll
            for (int i = 0; i < 4; ++i)
#pragma unroll
                for (int j = 0; j < 4; ++j)
                    acc[i][j] = fmaf(ar[i], br[j], acc[i][j]);
        }
    }

    float4 bvv = make_float4(0.f, 0.f, 0.f, 0.f);
    if (bias) bvv = *(const float4*)&bias[col0 + (tx << 2)];
#pragma unroll
    for (int i = 0; i < 4; ++i) {
        int m = row0 + (ty << 2) + i;
        float4 o;
        o.x = acc[i][0] + bvv.x;
        o.y = acc[i][1] + bvv.y;
        o.z = acc[i][2] + bvv.z;
        o.w = acc[i][3] + bvv.w;
        *(float4*)&C[(long)m * N + col0 + (tx << 2)] = o;
    }
}

// ---------------------------------------------------------------------------
// Init C(rows,64) with broadcast bias (or zero).
// ---------------------------------------------------------------------------
__global__ __launch_bounds__(256) void init_bias64(
    float* __restrict__ C, const float* __restrict__ bias, long n)
{
    long idx = (long)blockIdx.x * 256 + threadIdx.x;
    if (idx < n) C[idx] = bias ? bias[idx & 63] : 0.f;
}

// ---------------------------------------------------------------------------
// Prep: cast fp32 -> bf16
// ---------------------------------------------------------------------------
__global__ __launch_bounds__(256) void cast_bf16(
    const float* __restrict__ src, unsigned short* __restrict__ dst, long n)
{
    long i = ((long)blockIdx.x * 256 + threadIdx.x) * 4;
    if (i >= n) return;
    float4 v = *(const float4*)&src[i];
    ushort4 o;
    o.x = f2bf(v.x); o.y = f2bf(v.y); o.z = f2bf(v.z); o.w = f2bf(v.w);
    *(ushort4*)&dst[i] = o;
}

// ---------------------------------------------------------------------------
// Prep: transpose + cast: Wt[n][k] = (bf16) W[k][n].  W is RxC, Wt is CxR.
// grid: (R/32, C/32)
// ---------------------------------------------------------------------------
__global__ __launch_bounds__(256) void transpose_cast(
    const float* __restrict__ W, unsigned short* __restrict__ Wt, int R, int C)
{
    __shared__ float t[32][33];
    const int k0 = blockIdx.x * 32, n0 = blockIdx.y * 32;
    const int c = threadIdx.x & 31, r = threadIdx.x >> 5;  // r: 0..7
#pragma unroll
    for (int rr = r; rr < 32; rr += 8)
        t[rr][c] = W[(long)(k0 + rr) * C + n0 + c];
    __syncthreads();
#pragma unroll
    for (int rr = r; rr < 32; rr += 8)
        Wt[(long)(n0 + rr) * R + k0 + c] = f2bf(t[c][rr]);
}

// ---------------------------------------------------------------------------
// bf16 MFMA GEMM, B^T input: C(M,N) bf16 = ((A @ Bt^T) + bias) * oscale
// 128x128 tile, BK=64, 256 threads (4 waves, 64x64 quadrant each).
// ---------------------------------------------------------------------------
__global__ __launch_bounds__(256) void gemm_bt_bf16(
    const unsigned short* __restrict__ A, const unsigned short* __restrict__ Bt,
    const float* __restrict__ bias, unsigned short* __restrict__ C,
    int M, int N, int K, float oscale)
{
    __shared__ unsigned short As[128][72];
    __shared__ unsigned short Bs[128][72];

    const int tid  = threadIdx.x;
    const int row0 = blockIdx.y * 128;
    const int col0 = blockIdx.x * 128;
    const int w  = tid >> 6, L = tid & 63;
    const int wm = (w & 1) * 64, wn = (w >> 1) * 64;
    const int lr = tid >> 3;          // staging row (0..31, +32 steps)
    const int lc = (tid & 7) * 8;     // staging dim chunk (8 bf16 = 16 B)
    const int ml = L & 15, q8 = (L >> 4) * 8, q4 = (L >> 4) * 4;

    f32x4 acc[4][4];
#pragma unroll
    for (int i = 0; i < 4; ++i)
#pragma unroll
        for (int j = 0; j < 4; ++j)
            acc[i][j] = (f32x4){0.f, 0.f, 0.f, 0.f};

    for (int k0 = 0; k0 < K; k0 += 64) {
        __syncthreads();
#pragma unroll
        for (int rr = 0; rr < 128; rr += 32) {
            *(float4*)&As[lr + rr][lc] = *(const float4*)&A[(long)(row0 + lr + rr) * K + k0 + lc];
            *(float4*)&Bs[lr + rr][lc] = *(const float4*)&Bt[(long)(col0 + lr + rr) * K + k0 + lc];
        }
        __syncthreads();
#pragma unroll
        for (int kk = 0; kk < 64; kk += 32) {
            bf16x8 a[4], b[4];
#pragma unroll
            for (int i = 0; i < 4; ++i) a[i] = *(bf16x8*)&As[wm + i * 16 + ml][kk + q8];
#pragma unroll
            for (int j = 0; j < 4; ++j) b[j] = *(bf16x8*)&Bs[wn + j * 16 + ml][kk + q8];
#pragma unroll
            for (int i = 0; i < 4; ++i)
#pragma unroll
                for (int j = 0; j < 4; ++j)
                    acc[i][j] = __builtin_amdgcn_mfma_f32_16x16x32_bf16(a[i], b[j], acc[i][j], 0, 0, 0);
        }
    }

#pragma unroll
    for (int j = 0; j < 4; ++j) {
        const int col = col0 + wn + j * 16 + ml;
        const float bj = bias ? bias[col] : 0.f;
#pragma unroll
        for (int i = 0; i < 4; ++i) {
#pragma unroll
            for (int r = 0; r < 4; ++r) {
                const int row = row0 + wm + i * 16 + q4 + r;
                C[(long)row * N + col] = f2bf((acc[i][j][r] + bj) * oscale);
            }
        }
    }
}

// ---------------------------------------------------------------------------
// V projection, bf16 MFMA split-K: C(8192,64) fp32 += xb(8192,1024)[kchunk] @ Wvt^T
// grid: (M/128, K/256). Caller pre-inits C with bias.
// ---------------------------------------------------------------------------
__global__ __launch_bounds__(256) void gemm_v_bf16(
    const unsigned short* __restrict__ A, const unsigned short* __restrict__ Bt,
    float* __restrict__ C)
{
    __shared__ unsigned short As[128][72];
    __shared__ unsigned short Bs[64][72];

    const int tid  = threadIdx.x;
    const int row0 = blockIdx.x * 128;
    const int kbeg = blockIdx.y * 256;
    const int w = tid >> 6, L = tid & 63;
    const int ml = L & 15, q8 = (L >> 4) * 8, q4 = (L >> 4) * 4;
    const int ar = tid >> 3, ac = (tid & 7) * 8;
    const int br = tid >> 2, bc = (tid & 3) * 16;

    f32x4 acc[2][4];
#pragma unroll
    for (int i = 0; i < 2; ++i)
#pragma unroll
        for (int j = 0; j < 4; ++j) acc[i][j] = (f32x4){0.f, 0.f, 0.f, 0.f};

    for (int k0 = kbeg; k0 < kbeg + 256; k0 += 64) {
        __syncthreads();
#pragma unroll
        for (int rr = 0; rr < 128; rr += 32)
            *(float4*)&As[ar + rr][ac] = *(const float4*)&A[(long)(row0 + ar + rr) * HIDc + k0 + ac];
        *(float4*)&Bs[br][bc]     = *(const float4*)&Bt[(long)br * HIDc + k0 + bc];
        *(float4*)&Bs[br][bc + 8] = *(const float4*)&Bt[(long)br * HIDc + k0 + bc + 8];
        __syncthreads();
#pragma unroll
        for (int kk = 0; kk < 64; kk += 32) {
            bf16x8 a[2], b[4];
#pragma unroll
            for (int i = 0; i < 2; ++i) a[i] = *(bf16x8*)&As[w * 32 + i * 16 + ml][kk + q8];
#pragma unroll
            for (int j = 0; j < 4; ++j) b[j] = *(bf16x8*)&Bs[j * 16 + ml][kk + q8];
#pragma unroll
            for (int i = 0; i < 2; ++i)
#pragma unroll
                for (int j = 0; j < 4; ++j)
                    acc[i][j] = __builtin_amdgcn_mfma_f32_16x16x32_bf16(a[i], b[j], acc[i][j], 0, 0, 0);
        }
    }

#pragma unroll
    for (int i = 0; i < 2; ++i)
#pragma unroll
        for (int j = 0; j < 4; ++j)
#pragma unroll
            for (int r = 0; r < 4; ++r)
                atomicAdd(&C[(long)(row0 + w * 32 + i * 16 + q4 + r) * 64 + j * 16 + ml], acc[i][j][r]);
}

// ---------------------------------------------------------------------------
// Attention pass 1: softmax denominators. q pre-scaled by QSCALE so
// exp(s/8) = 2^(q'.k). Block: 128 q-rows x (b,h). K-tile loop with register
// prefetch (issue-early/write-late): next tile's loads fly under current MFMA.
// ---------------------------------------------------------------------------
__global__ __launch_bounds__(256) void attn_denom(
    const unsigned short* __restrict__ qb, const unsigned short* __restrict__ kb,
    float* __restrict__ linv)
{
    const int qt = blockIdx.x, h = blockIdx.y, b = blockIdx.z;
    __shared__ unsigned short Qs[128][72];
    __shared__ unsigned short Ks[64][72];

    const int tid = threadIdx.x;
    const int w = tid >> 6, L = tid & 63;
    const int ml = L & 15, q8 = (L >> 4) * 8, q4 = (L >> 4) * 4;
    const int ar = tid >> 3, ac = (tid & 7) * 8;
    const int kr = tid >> 2, kc = (tid & 3) * 16;

    // Stage 128-row Q slice once.
#pragma unroll
    for (int rr = 0; rr < 128; rr += 32)
        *(float4*)&Qs[ar + rr][ac] =
            *(const float4*)&qb[(long)(b * Tt + qt * 128 + ar + rr) * HIDc + h * HSc + ac];

    const unsigned short* kbase = kb + ((long)(b * Tt + kr) * HIDc + h * HSc + kc);
    float4 v0 = *(const float4*)kbase;
    float4 v1 = *(const float4*)(kbase + 8);

    float lacc[2][4] = {};

    for (int kt = 0; kt < Tt / 64; ++kt) {
        *(float4*)&Ks[kr][kc]     = v0;
        *(float4*)&Ks[kr][kc + 8] = v1;
        if (kt + 1 < Tt / 64) {
            const unsigned short* s = kbase + (long)(kt + 1) * 64 * HIDc;
            v0 = *(const float4*)s;
            v1 = *(const float4*)(s + 8);
        }
        __syncthreads();   // Ks(kt) (and Qs, first iter) visible

        f32x4 acc[2][4];
#pragma unroll
        for (int i = 0; i < 2; ++i)
#pragma unroll
            for (int j = 0; j < 4; ++j) acc[i][j] = (f32x4){0.f, 0.f, 0.f, 0.f};
#pragma unroll
        for (int kk = 0; kk < 64; kk += 32) {
            bf16x8 a[2], bfr[4];
#pragma unroll
            for (int i = 0; i < 2; ++i) a[i] = *(bf16x8*)&Qs[w * 32 + i * 16 + ml][kk + q8];
#pragma unroll
            for (int j = 0; j < 4; ++j) bfr[j] = *(bf16x8*)&Ks[j * 16 + ml][kk + q8];
#pragma unroll
            for (int i = 0; i < 2; ++i)
#pragma unroll
                for (int j = 0; j < 4; ++j)
                    acc[i][j] = __builtin_amdgcn_mfma_f32_16x16x32_bf16(a[i], bfr[j], acc[i][j], 0, 0, 0);
        }
#pragma unroll
        for (int i = 0; i < 2; ++i)
#pragma unroll
            for (int j = 0; j < 4; ++j)
#pragma unroll
                for (int r = 0; r < 4; ++r)
                    lacc[i][r] += fexp2(acc[i][j][r]);
        __syncthreads();   // all reads done before next Ks write
    }

#pragma unroll
    for (int i = 0; i < 2; ++i)
#pragma unroll
        for (int r = 0; r < 4; ++r) {
            float v = lacc[i][r];
            v += __shfl_xor(v, 1, 16);
            v += __shfl_xor(v, 2, 16);
            v += __shfl_xor(v, 4, 16);
            v += __shfl_xor(v, 8, 16);
            if (ml == 0)
                linv[((long)(b * NHc + h)) * Tt + qt * 128 + w * 32 + i * 16 + q4 + r] =
                    1.0f / (v * (float)NHc);
        }
}

// ---------------------------------------------------------------------------
// Attention pass 2: block = 64 q-rows x 128 k-cols. Loop heads with register
// prefetch of next head's Q/K (T14 issue-early/write-late); all 16 heads'
// 1/l staged once. Writes head-averaged attn tile only (PV moved to gemm_pv
// -- no atomics, no LDS overlay).
// ---------------------------------------------------------------------------
__global__ __launch_bounds__(256) void attn_avg_w(
    const unsigned short* __restrict__ qb, const unsigned short* __restrict__ kb,
    const float* __restrict__ linv, float* __restrict__ attn)
{
    const int ktg = blockIdx.x, qt = blockIdx.y, b = blockIdx.z;

    __shared__ unsigned short Qs[64][72];
    __shared__ unsigned short Ks[128][72];
    __shared__ float invsAll[NHc][64];

    const int tid = threadIdx.x;
    const int w = tid >> 6, L = tid & 63;
    const int ml = L & 15, q8 = (L >> 4) * 8, q4 = (L >> 4) * 4;
    const int rw = (w >> 1) * 32;     // q-row strip
    const int kh = (w & 1) * 64;      // k-col strip
    const int qr = tid >> 2, qc = (tid & 3) * 16;
    const int kr = tid >> 3, kc = (tid & 7) * 8;

    // Stage all 16 heads' 1/(l*NH) once: thread t -> head t>>4, rows (t&15)*4..+3
    {
        const int hh = tid >> 4, r4 = (tid & 15) * 4;
        *(float4*)&invsAll[hh][r4] =
            *(const float4*)&linv[((long)(b * NHc + hh)) * Tt + qt * 64 + r4];
    }

    const unsigned short* qbase = qb + ((long)(b * Tt + qt * 64 + qr) * HIDc + qc);
    const unsigned short* kbase = kb + ((long)(b * Tt + ktg * 128 + kr) * HIDc + kc);

    // Prefetch head 0 into registers.
    float4 q0 = *(const float4*)qbase;
    float4 q1 = *(const float4*)(qbase + 8);
    float4 kv[4];
#pragma unroll
    for (int rr = 0; rr < 4; ++rr)
        kv[rr] = *(const float4*)(kbase + (long)rr * 32 * HIDc);

    float pacc[2][4][4] = {};

    for (int h = 0; h < NHc; ++h) {
        // Write LDS from regs(h), then immediately issue loads for h+1 so the
        // global latency hides under this head's MFMA+exp.
        *(float4*)&Qs[qr][qc]     = q0;
        *(float4*)&Qs[qr][qc + 8] = q1;
#pragma unroll
        for (int rr = 0; rr < 4; ++rr)
            *(float4*)&Ks[kr + rr * 32][kc] = kv[rr];
        if (h + 1 < NHc) {
            const unsigned short* sq = qbase + (h + 1) * HSc;
            q0 = *(const float4*)sq;
            q1 = *(const float4*)(sq + 8);
            const unsigned short* sk = kbase + (h + 1) * HSc;
#pragma unroll
            for (int rr = 0; rr < 4; ++rr)
                kv[rr] = *(const float4*)(sk + (long)rr * 32 * HIDc);
        }
        __syncthreads();   // LDS(h) visible (first iter also covers invsAll)

        f32x4 acc[2][4];
#pragma unroll
        for (int i = 0; i < 2; ++i)
#pragma unroll
            for (int j = 0; j < 4; ++j) acc[i][j] = (f32x4){0.f, 0.f, 0.f, 0.f};
#pragma unroll
        for (int kk = 0; kk < 64; kk += 32) {
            bf16x8 a[2], bfr[4];
#pragma unroll
            for (int i = 0; i < 2; ++i) a[i] = *(bf16x8*)&Qs[rw + i * 16 + ml][kk + q8];
#pragma unroll
            for (int j = 0; j < 4; ++j) bfr[j] = *(bf16x8*)&Ks[kh + j * 16 + ml][kk + q8];
#pragma unroll
            for (int i = 0; i < 2; ++i)
#pragma unroll
                for (int j = 0; j < 4; ++j)
                    acc[i][j] = __builtin_amdgcn_mfma_f32_16x16x32_bf16(a[i], bfr[j], acc[i][j], 0, 0, 0);
        }
        float ivr[2][4];
        *(float4*)&ivr[0][0] = *(const float4*)&invsAll[h][rw + q4];
        *(float4*)&ivr[1][0] = *(const float4*)&invsAll[h][rw + 16 + q4];
#pragma unroll
        for (int i = 0; i < 2; ++i)
#pragma unroll
            for (int j = 0; j < 4; ++j)
#pragma unroll
                for (int r = 0; r < 4; ++r)
                    pacc[i][j][r] += fexp2(acc[i][j][r]) * ivr[i][r];
        __syncthreads();   // reads of LDS(h) done before next head's write
    }

    // Write head-averaged attn tile (fp32).
#pragma unroll
    for (int i = 0; i < 2; ++i)
#pragma unroll
        for (int j = 0; j < 4; ++j)
#pragma unroll
            for (int r = 0; r < 4; ++r) {
                const int qrow = rw + i * 16 + q4 + r;
                const int col  = kh + j * 16 + ml;
                attn[((long)(b * Tt + qt * 64 + qrow)) * Tt + ktg * 128 + col] = pacc[i][j][r];
            }
}

// ---------------------------------------------------------------------------
// PV: o1{a,b}(b,64q,64d) = attn[b](64q, khalf*1024:+1024) @ V[b].
// attn is L3-hot (just written). V pre-transposed to bf16 vT[b][d][k].
// Split-K=2 into two buffers (summed in gemm_f32) -> zero atomics.
// grid: (T/64, 2, B). Register-prefetched staging pipeline.
// ---------------------------------------------------------------------------
__global__ __launch_bounds__(256) void gemm_pv(
    const float* __restrict__ attn, const unsigned short* __restrict__ vT,
    float* __restrict__ o1a, float* __restrict__ o1b)
{
    const int qt = blockIdx.x, khalf = blockIdx.y, b = blockIdx.z;
    float* o1p = khalf ? o1b : o1a;

    __shared__ unsigned short Ps[64][72];
    __shared__ unsigned short Vs[64][72];

    const int tid = threadIdx.x;
    const int w = tid >> 6, L = tid & 63;
    const int ml = L & 15, q8 = (L >> 4) * 8, q4 = (L >> 4) * 4;
    const int wq = (w >> 1) * 32, wd = (w & 1) * 32;
    const int pr = tid >> 2, pc = (tid & 3) * 16;   // P staging: row, 16-col chunk
    const int vr = tid >> 3, vc = (tid & 7) * 8;    // V staging: d-row (0..31,+32), 8-k chunk

    const float* abase = attn + ((long)(b * Tt + qt * 64 + pr)) * Tt + khalf * 1024 + pc;
    const unsigned short* vbase = vT + ((long)(b * HSc + vr)) * Tt + khalf * 1024 + vc;

    float4 pf[4], vf0, vf1;
#pragma unroll
    for (int i = 0; i < 4; ++i) pf[i] = *(const float4*)(abase + i * 4);
    vf0 = *(const float4*)vbase;
    vf1 = *(const float4*)(vbase + (long)32 * Tt);

    f32x4 acc[2][2];
#pragma unroll
    for (int i = 0; i < 2; ++i)
#pragma unroll
        for (int j = 0; j < 2; ++j) acc[i][j] = (f32x4){0.f, 0.f, 0.f, 0.f};

    for (int t = 0; t < 16; ++t) {
        __align__(16) unsigned short tmp[16];
#pragma unroll
        for (int i = 0; i < 4; ++i) {
            tmp[i * 4 + 0] = f2bf(pf[i].x);
            tmp[i * 4 + 1] = f2bf(pf[i].y);
            tmp[i * 4 + 2] = f2bf(pf[i].z);
            tmp[i * 4 + 3] = f2bf(pf[i].w);
        }
        *(float4*)&Ps[pr][pc]      = *(float4*)&tmp[0];
        *(float4*)&Ps[pr][pc + 8]  = *(float4*)&tmp[8];
        *(float4*)&Vs[vr][vc]      = vf0;
        *(float4*)&Vs[vr + 32][vc] = vf1;
        if (t + 1 < 16) {
#pragma unroll
            for (int i = 0; i < 4; ++i)
                pf[i] = *(const float4*)(abase + (t + 1) * 64 + i * 4);
            vf0 = *(const float4*)(vbase + (t + 1) * 64);
            vf1 = *(const float4*)(vbase + (long)32 * Tt + (t + 1) * 64);
        }
        __syncthreads();
#pragma unroll
        for (int kk = 0; kk < 64; kk += 32) {
            bf16x8 a0 = *(bf16x8*)&Ps[wq + ml][kk + q8];
            bf16x8 a1 = *(bf16x8*)&Ps[wq + 16 + ml][kk + q8];
            bf16x8 b0 = *(bf16x8*)&Vs[wd + ml][kk + q8];
            bf16x8 b1 = *(bf16x8*)&Vs[wd + 16 + ml][kk + q8];
            acc[0][0] = __builtin_amdgcn_mfma_f32_16x16x32_bf16(a0, b0, acc[0][0], 0, 0, 0);
            acc[0][1] = __builtin_amdgcn_mfma_f32_16x16x32_bf16(a0, b1, acc[0][1], 0, 0, 0);
            acc[1][0] = __builtin_amdgcn_mfma_f32_16x16x32_bf16(a1, b0, acc[1][0], 0, 0, 0);
            acc[1][1] = __builtin_amdgcn_mfma_f32_16x16x32_bf16(a1, b1, acc[1][1], 0, 0, 0);
        }
        __syncthreads();
    }

#pragma unroll
    for (int i = 0; i < 2; ++i)
#pragma unroll
        for (int j = 0; j < 2; ++j)
#pragma unroll
            for (int r = 0; r < 4; ++r)
                o1p[((long)(b * Tt + qt * 64 + wq + i * 16 + q4 + r)) * HSc + wd + j * 16 + ml] =
                    acc[i][j][r];
}

// ---------------------------------------------------------------------------
extern "C" void kernel_launch(void* const* d_in, const int* in_sizes, int n_in,
                              void* d_out, int out_size, void* d_ws, size_t ws_size,
                              hipStream_t stream)
{
    const float* x  = (const float*)d_in[0];
    const float* Wq = (const float*)d_in[1];
    const float* bq = (const float*)d_in[2];
    const float* Wk = (const float*)d_in[3];
    const float* bk = (const float*)d_in[4];
    const float* Wv = (const float*)d_in[5];
    const float* bv = (const float*)d_in[6];
    const float* Wo = (const float*)d_in[7];
    const float* bo = (const float*)d_in[8];

    float* out  = (float*)d_out;                    // B*T*HID
    float* attn = out + (long)BTc * HIDc;           // B*T*T

    // workspace: xb | Wqt | Wkt | Wvt | qb | kb | v | linv | o1a  (~59 MB)
    // dead-buffer reuse: vbT overlays Wqt (free after Q proj);
    //                    o1b overlays Wkt (free after K proj; 2 MB exactly).
    unsigned short* xb  = (unsigned short*)d_ws;
    unsigned short* Wqt = xb  + (long)BTc * HIDc;
    unsigned short* Wkt = Wqt + (long)HIDc * HIDc;
    unsigned short* Wvt = Wkt + (long)HIDc * HIDc;
    unsigned short* qb  = Wvt + (long)HSc * HIDc;
    unsigned short* kb  = qb  + (long)BTc * HIDc;
    float* v    = (float*)(kb + (long)BTc * HIDc);
    float* linv = v    + (long)BTc * HSc;
    float* o1a  = linv + (long)Bc * NHc * Tt;
    unsigned short* vbT = Wqt;          // B*HS*T bf16 = 1 MB  (<= 2 MB slot)
    float* o1b = (float*)Wkt;           // B*T*HS fp32 = 2 MB  (== 2 MB slot)

    dim3 blk(256);

    // prep: casts + weight transposes + V-bias init (ws is poisoned)
    cast_bf16<<<dim3((BTc * HIDc) / 1024), blk, 0, stream>>>(x, xb, (long)BTc * HIDc);
    transpose_cast<<<dim3(32, 32), blk, 0, stream>>>(Wq, Wqt, HIDc, HIDc);
    transpose_cast<<<dim3(32, 32), blk, 0, stream>>>(Wk, Wkt, HIDc, HIDc);
    transpose_cast<<<dim3(32, 2),  blk, 0, stream>>>(Wv, Wvt, HIDc, HSc);
    init_bias64<<<dim3((BTc * HSc) / 256), blk, 0, stream>>>(v, bv, (long)BTc * HSc);

    // Q/K projections (bf16 MFMA). Q pre-scaled by 0.125*log2(e) for exp2.
    gemm_bt_bf16<<<dim3(HIDc / 128, BTc / 128), blk, 0, stream>>>(xb, Wqt, bq, qb, BTc, HIDc, HIDc, QSCALE);
    gemm_bt_bf16<<<dim3(HIDc / 128, BTc / 128), blk, 0, stream>>>(xb, Wkt, bk, kb, BTc, HIDc, HIDc, 1.0f);

    // V projection: bf16 MFMA split-K (atomics into fp32 v, bias-preinit'd)
    gemm_v_bf16<<<dim3(BTc / 128, HIDc / 256), blk, 0, stream>>>(xb, Wvt, v);

    // v (B,T,64) fp32 -> vT (B,64,T) bf16 for the PV GEMM's B-operand.
    for (int bi = 0; bi < Bc; ++bi)
        transpose_cast<<<dim3(Tt / 32, HSc / 32), blk, 0, stream>>>(
            v + (long)bi * Tt * HSc, vbT + (long)bi * HSc * Tt, Tt, HSc);

    // pass 1: softmax denominators (128 q-rows per block, prefetched K tiles)
    attn_denom<<<dim3(Tt / 128, NHc, Bc), blk, 0, stream>>>(qb, kb, linv);

    // pass 2: head-averaged attn tile only (prefetched Q/K per head)
    attn_avg_w<<<dim3(Tt / 128, Tt / 64, Bc), blk, 0, stream>>>(qb, kb, linv, attn);

    // PV from the L3-hot attn: o1a/o1b partials, no atomics
    gemm_pv<<<dim3(Tt / 64, 2, Bc), blk, 0, stream>>>(attn, vbT, o1a, o1b);

    // out = (o1a + o1b) @ Wo + bo
    gemm_f32<<<dim3(HIDc / 64, BTc / 64), blk, 0, stream>>>(o1a, o1b, Wo, bo, out, BTc, HIDc, HSc);
}

// Round 2
// 460.484 us; speedup vs baseline: 1.0134x; 1.0134x over previous
//
#include <hip/hip_runtime.h>
#include <math.h>

// Problem constants (fixed by the reference)
#define Bc   4
#define Tt   2048
#define HIDc 1024
#define NHc  16
#define HSc  64
#define BTc  (Bc * Tt)          // 8192
#define QSCALE 0.18033688011112042f   // 0.125 * log2(e): folded into q so exp(s/8)=2^acc

typedef __attribute__((ext_vector_type(8))) short bf16x8;   // 8 bf16 = 4 VGPRs
typedef __attribute__((ext_vector_type(4))) float f32x4;

__device__ __forceinline__ unsigned short f2bf(float f) {
    unsigned u = __float_as_uint(f);
    u = u + 0x7FFFu + ((u >> 16) & 1u);   // round-to-nearest-even
    return (unsigned short)(u >> 16);
}

__device__ __forceinline__ float fexp2(float x) {
#if __has_builtin(__builtin_amdgcn_exp2f)
    return __builtin_amdgcn_exp2f(x);
#else
    float r; asm("v_exp_f32 %0, %1" : "=v"(r) : "v"(x)); return r;
#endif
}

// ---------------------------------------------------------------------------
// fp32 GEMM (Wo epilogue): C = (A + A2) @ B + bias, 64x64 tile.
// A2 (optional) is the second split-K partial from gemm_pv.
// ---------------------------------------------------------------------------
__global__ __launch_bounds__(256) void gemm_f32(
    const float* __restrict__ A, const float* __restrict__ A2,
    const float* __restrict__ Bm, const float* __restrict__ bias,
    float* __restrict__ C, int M, int N, int K)
{
    __shared__ float As[16][64];
    __shared__ float Bs[16][64];

    const int tid  = threadIdx.x;
    const int tx   = tid & 15;
    const int ty   = tid >> 4;
    const int row0 = blockIdx.y * 64;
    const int col0 = blockIdx.x * 64;

    const int la_r = tid >> 2;
    const int la_c = (tid & 3) << 2;
    const int lb_r = tid >> 4;
    const int lb_c = (tid & 15) << 2;

    float acc[4][4] = {};

    for (int k0 = 0; k0 < K; k0 += 16) {
        float4 av = *(const float4*)&A[(long)(row0 + la_r) * K + k0 + la_c];
        if (A2) {
            float4 a2 = *(const float4*)&A2[(long)(row0 + la_r) * K + k0 + la_c];
            av.x += a2.x; av.y += a2.y; av.z += a2.z; av.w += a2.w;
        }
        float4 bv = *(const float4*)&Bm[(long)(k0 + lb_r) * N + col0 + lb_c];
        __syncthreads();
        As[la_c + 0][la_r] = av.x;
        As[la_c + 1][la_r] = av.y;
        As[la_c + 2][la_r] = av.z;
        As[la_c + 3][la_r] = av.w;
        *(float4*)&Bs[lb_r][lb_c] = bv;
        __syncthreads();
#pragma unroll
        for (int kk = 0; kk < 16; ++kk) {
            float4 a = *(float4*)&As[kk][ty << 2];
            float4 b = *(float4*)&Bs[kk][tx << 2];
            float ar[4] = {a.x, a.y, a.z, a.w};
            float br[4] = {b.x, b.y, b.z, b.w};
#pragma unroll
            for (int i = 0; i < 4; ++i)
#pragma unroll
                for (int j = 0; j < 4; ++j)
                    acc[i][j] = fmaf(ar[i], br[j], acc[i][j]);
        }
    }

    float4 bvv = make_float4(0.f, 0.f, 0.f, 0.f);
    if (bias) bvv = *(const float4*)&bias[col0 + (tx << 2)];
#pragma unroll
    for (int i = 0; i < 4; ++i) {
        int m = row0 + (ty << 2) + i;
        float4 o;
        o.x = acc[i][0] + bvv.x;
        o.y = acc[i][1] + bvv.y;
        o.z = acc[i][2] + bvv.z;
        o.w = acc[i][3] + bvv.w;
        *(float4*)&C[(long)m * N + col0 + (tx << 2)] = o;
    }
}

// ---------------------------------------------------------------------------
// Init C(rows,64) with broadcast bias (or zero).
// ---------------------------------------------------------------------------
__global__ __launch_bounds__(256) void init_bias64(
    float* __restrict__ C, const float* __restrict__ bias, long n)
{
    long idx = (long)blockIdx.x * 256 + threadIdx.x;
    if (idx < n) C[idx] = bias ? bias[idx & 63] : 0.f;
}

// ---------------------------------------------------------------------------
// Prep: cast fp32 -> bf16
// ---------------------------------------------------------------------------
__global__ __launch_bounds__(256) void cast_bf16(
    const float* __restrict__ src, unsigned short* __restrict__ dst, long n)
{
    long i = ((long)blockIdx.x * 256 + threadIdx.x) * 4;
    if (i >= n) return;
    float4 v = *(const float4*)&src[i];
    ushort4 o;
    o.x = f2bf(v.x); o.y = f2bf(v.y); o.z = f2bf(v.z); o.w = f2bf(v.w);
    *(ushort4*)&dst[i] = o;
}

// ---------------------------------------------------------------------------
// Prep: transpose + cast: Wt[n][k] = (bf16) W[k][n].  W is RxC, Wt is CxR.
// grid: (R/32, C/32)
// ---------------------------------------------------------------------------
__global__ __launch_bounds__(256) void transpose_cast(
    const float* __restrict__ W, unsigned short* __restrict__ Wt, int R, int C)
{
    __shared__ float t[32][33];
    const int k0 = blockIdx.x * 32, n0 = blockIdx.y * 32;
    const int c = threadIdx.x & 31, r = threadIdx.x >> 5;  // r: 0..7
#pragma unroll
    for (int rr = r; rr < 32; rr += 8)
        t[rr][c] = W[(long)(k0 + rr) * C + n0 + c];
    __syncthreads();
#pragma unroll
    for (int rr = r; rr < 32; rr += 8)
        Wt[(long)(n0 + rr) * R + k0 + c] = f2bf(t[c][rr]);
}

// ---------------------------------------------------------------------------
// bf16 MFMA GEMM, B^T input: C(M,N) bf16 = ((A @ Bt^T) + bias) * oscale
// 128x128 tile, BK=64, 256 threads (4 waves, 64x64 quadrant each).
// ---------------------------------------------------------------------------
__global__ __launch_bounds__(256) void gemm_bt_bf16(
    const unsigned short* __restrict__ A, const unsigned short* __restrict__ Bt,
    const float* __restrict__ bias, unsigned short* __restrict__ C,
    int M, int N, int K, float oscale)
{
    __shared__ unsigned short As[128][72];
    __shared__ unsigned short Bs[128][72];

    const int tid  = threadIdx.x;
    const int row0 = blockIdx.y * 128;
    const int col0 = blockIdx.x * 128;
    const int w  = tid >> 6, L = tid & 63;
    const int wm = (w & 1) * 64, wn = (w >> 1) * 64;
    const int lr = tid >> 3;          // staging row (0..31, +32 steps)
    const int lc = (tid & 7) * 8;     // staging dim chunk (8 bf16 = 16 B)
    const int ml = L & 15, q8 = (L >> 4) * 8, q4 = (L >> 4) * 4;

    f32x4 acc[4][4];
#pragma unroll
    for (int i = 0; i < 4; ++i)
#pragma unroll
        for (int j = 0; j < 4; ++j)
            acc[i][j] = (f32x4){0.f, 0.f, 0.f, 0.f};

    for (int k0 = 0; k0 < K; k0 += 64) {
        __syncthreads();
#pragma unroll
        for (int rr = 0; rr < 128; rr += 32) {
            *(float4*)&As[lr + rr][lc] = *(const float4*)&A[(long)(row0 + lr + rr) * K + k0 + lc];
            *(float4*)&Bs[lr + rr][lc] = *(const float4*)&Bt[(long)(col0 + lr + rr) * K + k0 + lc];
        }
        __syncthreads();
#pragma unroll
        for (int kk = 0; kk < 64; kk += 32) {
            bf16x8 a[4], b[4];
#pragma unroll
            for (int i = 0; i < 4; ++i) a[i] = *(bf16x8*)&As[wm + i * 16 + ml][kk + q8];
#pragma unroll
            for (int j = 0; j < 4; ++j) b[j] = *(bf16x8*)&Bs[wn + j * 16 + ml][kk + q8];
#pragma unroll
            for (int i = 0; i < 4; ++i)
#pragma unroll
                for (int j = 0; j < 4; ++j)
                    acc[i][j] = __builtin_amdgcn_mfma_f32_16x16x32_bf16(a[i], b[j], acc[i][j], 0, 0, 0);
        }
    }

#pragma unroll
    for (int j = 0; j < 4; ++j) {
        const int col = col0 + wn + j * 16 + ml;
        const float bj = bias ? bias[col] : 0.f;
#pragma unroll
        for (int i = 0; i < 4; ++i) {
#pragma unroll
            for (int r = 0; r < 4; ++r) {
                const int row = row0 + wm + i * 16 + q4 + r;
                C[(long)row * N + col] = f2bf((acc[i][j][r] + bj) * oscale);
            }
        }
    }
}

// ---------------------------------------------------------------------------
// V projection, bf16 MFMA split-K: C(8192,64) fp32 += xb(8192,1024)[kchunk] @ Wvt^T
// grid: (M/128, K/256). Caller pre-inits C with bias.
// ---------------------------------------------------------------------------
__global__ __launch_bounds__(256) void gemm_v_bf16(
    const unsigned short* __restrict__ A, const unsigned short* __restrict__ Bt,
    float* __restrict__ C)
{
    __shared__ unsigned short As[128][72];
    __shared__ unsigned short Bs[64][72];

    const int tid  = threadIdx.x;
    const int row0 = blockIdx.x * 128;
    const int kbeg = blockIdx.y * 256;
    const int w = tid >> 6, L = tid & 63;
    const int ml = L & 15, q8 = (L >> 4) * 8, q4 = (L >> 4) * 4;
    const int ar = tid >> 3, ac = (tid & 7) * 8;
    const int br = tid >> 2, bc = (tid & 3) * 16;

    f32x4 acc[2][4];
#pragma unroll
    for (int i = 0; i < 2; ++i)
#pragma unroll
        for (int j = 0; j < 4; ++j) acc[i][j] = (f32x4){0.f, 0.f, 0.f, 0.f};

    for (int k0 = kbeg; k0 < kbeg + 256; k0 += 64) {
        __syncthreads();
#pragma unroll
        for (int rr = 0; rr < 128; rr += 32)
            *(float4*)&As[ar + rr][ac] = *(const float4*)&A[(long)(row0 + ar + rr) * HIDc + k0 + ac];
        *(float4*)&Bs[br][bc]     = *(const float4*)&Bt[(long)br * HIDc + k0 + bc];
        *(float4*)&Bs[br][bc + 8] = *(const float4*)&Bt[(long)br * HIDc + k0 + bc + 8];
        __syncthreads();
#pragma unroll
        for (int kk = 0; kk < 64; kk += 32) {
            bf16x8 a[2], b[4];
#pragma unroll
            for (int i = 0; i < 2; ++i) a[i] = *(bf16x8*)&As[w * 32 + i * 16 + ml][kk + q8];
#pragma unroll
            for (int j = 0; j < 4; ++j) b[j] = *(bf16x8*)&Bs[j * 16 + ml][kk + q8];
#pragma unroll
            for (int i = 0; i < 2; ++i)
#pragma unroll
                for (int j = 0; j < 4; ++j)
                    acc[i][j] = __builtin_amdgcn_mfma_f32_16x16x32_bf16(a[i], b[j], acc[i][j], 0, 0, 0);
        }
    }

#pragma unroll
    for (int i = 0; i < 2; ++i)
#pragma unroll
        for (int j = 0; j < 4; ++j)
#pragma unroll
            for (int r = 0; r < 4; ++r)
                atomicAdd(&C[(long)(row0 + w * 32 + i * 16 + q4 + r) * 64 + j * 16 + ml], acc[i][j][r]);
}

// ---------------------------------------------------------------------------
// Attention pass 1: softmax denominators. q pre-scaled by QSCALE so
// exp(s/8) = 2^(q'.k). Block: 128 q-rows x (b,h). K-tile loop with register
// prefetch (issue-early/write-late): next tile's loads fly under current MFMA.
// ---------------------------------------------------------------------------
__global__ __launch_bounds__(256) void attn_denom(
    const unsigned short* __restrict__ qb, const unsigned short* __restrict__ kb,
    float* __restrict__ linv)
{
    const int qt = blockIdx.x, h = blockIdx.y, b = blockIdx.z;
    __shared__ unsigned short Qs[128][72];
    __shared__ unsigned short Ks[64][72];

    const int tid = threadIdx.x;
    const int w = tid >> 6, L = tid & 63;
    const int ml = L & 15, q8 = (L >> 4) * 8, q4 = (L >> 4) * 4;
    const int ar = tid >> 3, ac = (tid & 7) * 8;
    const int kr = tid >> 2, kc = (tid & 3) * 16;

    // Stage 128-row Q slice once.
#pragma unroll
    for (int rr = 0; rr < 128; rr += 32)
        *(float4*)&Qs[ar + rr][ac] =
            *(const float4*)&qb[(long)(b * Tt + qt * 128 + ar + rr) * HIDc + h * HSc + ac];

    const unsigned short* kbase = kb + ((long)(b * Tt + kr) * HIDc + h * HSc + kc);
    float4 v0 = *(const float4*)kbase;
    float4 v1 = *(const float4*)(kbase + 8);

    float lacc[2][4] = {};

    for (int kt = 0; kt < Tt / 64; ++kt) {
        *(float4*)&Ks[kr][kc]     = v0;
        *(float4*)&Ks[kr][kc + 8] = v1;
        if (kt + 1 < Tt / 64) {
            const unsigned short* s = kbase + (long)(kt + 1) * 64 * HIDc;
            v0 = *(const float4*)s;
            v1 = *(const float4*)(s + 8);
        }
        __syncthreads();   // Ks(kt) (and Qs, first iter) visible

        f32x4 acc[2][4];
#pragma unroll
        for (int i = 0; i < 2; ++i)
#pragma unroll
            for (int j = 0; j < 4; ++j) acc[i][j] = (f32x4){0.f, 0.f, 0.f, 0.f};
#pragma unroll
        for (int kk = 0; kk < 64; kk += 32) {
            bf16x8 a[2], bfr[4];
#pragma unroll
            for (int i = 0; i < 2; ++i) a[i] = *(bf16x8*)&Qs[w * 32 + i * 16 + ml][kk + q8];
#pragma unroll
            for (int j = 0; j < 4; ++j) bfr[j] = *(bf16x8*)&Ks[j * 16 + ml][kk + q8];
#pragma unroll
            for (int i = 0; i < 2; ++i)
#pragma unroll
                for (int j = 0; j < 4; ++j)
                    acc[i][j] = __builtin_amdgcn_mfma_f32_16x16x32_bf16(a[i], bfr[j], acc[i][j], 0, 0, 0);
        }
#pragma unroll
        for (int i = 0; i < 2; ++i)
#pragma unroll
            for (int j = 0; j < 4; ++j)
#pragma unroll
                for (int r = 0; r < 4; ++r)
                    lacc[i][r] += fexp2(acc[i][j][r]);
        __syncthreads();   // all reads done before next Ks write
    }

#pragma unroll
    for (int i = 0; i < 2; ++i)
#pragma unroll
        for (int r = 0; r < 4; ++r) {
            float v = lacc[i][r];
            v += __shfl_xor(v, 1, 16);
            v += __shfl_xor(v, 2, 16);
            v += __shfl_xor(v, 4, 16);
            v += __shfl_xor(v, 8, 16);
            if (ml == 0)
                linv[((long)(b * NHc + h)) * Tt + qt * 128 + w * 32 + i * 16 + q4 + r] =
                    1.0f / (v * (float)NHc);
        }
}

// ---------------------------------------------------------------------------
// Attention pass 2: block = 64 q-rows x 128 k-cols. Loop heads with register
// prefetch of next head's Q/K; all 16 heads' 1/l staged once.
// EPILOGUE (round-2 change): pacc is bounced through an overlaid fp32 LDS
// tile [64][128] so every global store is a fully-covered, line-aligned
// wide burst (each global_store_dwordx4 covers two complete 512 B row
// segments) instead of 32 scattered 4 B/lane half-line stores -- probing the
// 7.7x WRITE_SIZE amplification seen in rounds 0/1.
// ---------------------------------------------------------------------------
__global__ __launch_bounds__(256) void attn_avg_w(
    const unsigned short* __restrict__ qb, const unsigned short* __restrict__ kb,
    const float* __restrict__ linv, float* __restrict__ attn)
{
    const int ktg = blockIdx.x, qt = blockIdx.y, b = blockIdx.z;

    __shared__ __align__(16) unsigned char smem[32768];
    unsigned short (*Qs)[72]  = (unsigned short(*)[72])smem;             // 64x72  (9216 B)
    unsigned short (*Ks)[72]  = (unsigned short(*)[72])(smem + 9216);    // 128x72 (18432 B)
    float (*invsAll)[64]      = (float(*)[64])(smem + 27648);            // 16x64  (4096 B)
    float* tile               = (float*)smem;                            // 64x128 fp32 overlay

    const int tid = threadIdx.x;
    const int w = tid >> 6, L = tid & 63;
    const int ml = L & 15, q8 = (L >> 4) * 8, q4 = (L >> 4) * 4;
    const int rw = (w >> 1) * 32;     // q-row strip
    const int kh = (w & 1) * 64;      // k-col strip
    const int qr = tid >> 2, qc = (tid & 3) * 16;
    const int kr = tid >> 3, kc = (tid & 7) * 8;

    // Stage all 16 heads' 1/(l*NH) once: thread t -> head t>>4, rows (t&15)*4..+3
    {
        const int hh = tid >> 4, r4 = (tid & 15) * 4;
        *(float4*)&invsAll[hh][r4] =
            *(const float4*)&linv[((long)(b * NHc + hh)) * Tt + qt * 64 + r4];
    }

    const unsigned short* qbase = qb + ((long)(b * Tt + qt * 64 + qr) * HIDc + qc);
    const unsigned short* kbase = kb + ((long)(b * Tt + ktg * 128 + kr) * HIDc + kc);

    // Prefetch head 0 into registers.
    float4 q0 = *(const float4*)qbase;
    float4 q1 = *(const float4*)(qbase + 8);
    float4 kv[4];
#pragma unroll
    for (int rr = 0; rr < 4; ++rr)
        kv[rr] = *(const float4*)(kbase + (long)rr * 32 * HIDc);

    float pacc[2][4][4] = {};

    for (int h = 0; h < NHc; ++h) {
        // Write LDS from regs(h), then immediately issue loads for h+1 so the
        // global latency hides under this head's MFMA+exp.
        *(float4*)&Qs[qr][qc]     = q0;
        *(float4*)&Qs[qr][qc + 8] = q1;
#pragma unroll
        for (int rr = 0; rr < 4; ++rr)
            *(float4*)&Ks[kr + rr * 32][kc] = kv[rr];
        if (h + 1 < NHc) {
            const unsigned short* sq = qbase + (h + 1) * HSc;
            q0 = *(const float4*)sq;
            q1 = *(const float4*)(sq + 8);
            const unsigned short* sk = kbase + (h + 1) * HSc;
#pragma unroll
            for (int rr = 0; rr < 4; ++rr)
                kv[rr] = *(const float4*)(sk + (long)rr * 32 * HIDc);
        }
        __syncthreads();   // LDS(h) visible (first iter also covers invsAll)

        f32x4 acc[2][4];
#pragma unroll
        for (int i = 0; i < 2; ++i)
#pragma unroll
            for (int j = 0; j < 4; ++j) acc[i][j] = (f32x4){0.f, 0.f, 0.f, 0.f};
#pragma unroll
        for (int kk = 0; kk < 64; kk += 32) {
            bf16x8 a[2], bfr[4];
#pragma unroll
            for (int i = 0; i < 2; ++i) a[i] = *(bf16x8*)&Qs[rw + i * 16 + ml][kk + q8];
#pragma unroll
            for (int j = 0; j < 4; ++j) bfr[j] = *(bf16x8*)&Ks[kh + j * 16 + ml][kk + q8];
#pragma unroll
            for (int i = 0; i < 2; ++i)
#pragma unroll
                for (int j = 0; j < 4; ++j)
                    acc[i][j] = __builtin_amdgcn_mfma_f32_16x16x32_bf16(a[i], bfr[j], acc[i][j], 0, 0, 0);
        }
        float ivr[2][4];
        *(float4*)&ivr[0][0] = *(const float4*)&invsAll[h][rw + q4];
        *(float4*)&ivr[1][0] = *(const float4*)&invsAll[h][rw + 16 + q4];
#pragma unroll
        for (int i = 0; i < 2; ++i)
#pragma unroll
            for (int j = 0; j < 4; ++j)
#pragma unroll
                for (int r = 0; r < 4; ++r)
                    pacc[i][j][r] += fexp2(acc[i][j][r]) * ivr[i][r];
        __syncthreads();   // reads of LDS(h) done before next head's write
    }
    // (trailing __syncthreads of last iter: all Qs/Ks/invsAll reads complete;
    //  safe to overlay with the fp32 tile)

    // Scatter pacc into the LDS tile (fragment layout; 4-way bank alias, cheap).
#pragma unroll
    for (int i = 0; i < 2; ++i)
#pragma unroll
        for (int j = 0; j < 4; ++j)
#pragma unroll
            for (int r = 0; r < 4; ++r) {
                const int qrow = rw + i * 16 + q4 + r;
                const int col  = kh + j * 16 + ml;
                tile[qrow * 128 + col] = pacc[i][j][r];
            }
    __syncthreads();

    // Wide, fully-coalesced store: thread t handles float4 chunks; each wave
    // instruction covers two complete 512 B row segments (128 B lines fully
    // written within one instruction).
    const long outbase = ((long)(b * Tt + qt * 64)) * Tt + ktg * 128;
#pragma unroll
    for (int e = 0; e < 8; ++e) {
        const int idx  = e * 1024 + tid * 4;   // float index within 64x128 tile
        const int rrow = idx >> 7;
        const int ccol = idx & 127;
        float4 val = *(const float4*)&tile[idx];
        *(float4*)&attn[outbase + (long)rrow * Tt + ccol] = val;
    }
}

// ---------------------------------------------------------------------------
// PV: o1{a,b}(b,64q,64d) = attn[b](64q, khalf*1024:+1024) @ V[b].
// attn is L3-hot (just written). V pre-transposed to bf16 vT[b][d][k].
// Split-K=2 into two buffers (summed in gemm_f32) -> zero atomics.
// grid: (T/64, 2, B). Register-prefetched staging pipeline.
// ---------------------------------------------------------------------------
__global__ __launch_bounds__(256) void gemm_pv(
    const float* __restrict__ attn, const unsigned short* __restrict__ vT,
    float* __restrict__ o1a, float* __restrict__ o1b)
{
    const int qt = blockIdx.x, khalf = blockIdx.y, b = blockIdx.z;
    float* o1p = khalf ? o1b : o1a;

    __shared__ unsigned short Ps[64][72];
    __shared__ unsigned short Vs[64][72];

    const int tid = threadIdx.x;
    const int w = tid >> 6, L = tid & 63;
    const int ml = L & 15, q8 = (L >> 4) * 8, q4 = (L >> 4) * 4;
    const int wq = (w >> 1) * 32, wd = (w & 1) * 32;
    const int pr = tid >> 2, pc = (tid & 3) * 16;   // P staging: row, 16-col chunk
    const int vr = tid >> 3, vc = (tid & 7) * 8;    // V staging: d-row (0..31,+32), 8-k chunk

    const float* abase = attn + ((long)(b * Tt + qt * 64 + pr)) * Tt + khalf * 1024 + pc;
    const unsigned short* vbase = vT + ((long)(b * HSc + vr)) * Tt + khalf * 1024 + vc;

    float4 pf[4], vf0, vf1;
#pragma unroll
    for (int i = 0; i < 4; ++i) pf[i] = *(const float4*)(abase + i * 4);
    vf0 = *(const float4*)vbase;
    vf1 = *(const float4*)(vbase + (long)32 * Tt);

    f32x4 acc[2][2];
#pragma unroll
    for (int i = 0; i < 2; ++i)
#pragma unroll
        for (int j = 0; j < 2; ++j) acc[i][j] = (f32x4){0.f, 0.f, 0.f, 0.f};

    for (int t = 0; t < 16; ++t) {
        __align__(16) unsigned short tmp[16];
#pragma unroll
        for (int i = 0; i < 4; ++i) {
            tmp[i * 4 + 0] = f2bf(pf[i].x);
            tmp[i * 4 + 1] = f2bf(pf[i].y);
            tmp[i * 4 + 2] = f2bf(pf[i].z);
            tmp[i * 4 + 3] = f2bf(pf[i].w);
        }
        *(float4*)&Ps[pr][pc]      = *(float4*)&tmp[0];
        *(float4*)&Ps[pr][pc + 8]  = *(float4*)&tmp[8];
        *(float4*)&Vs[vr][vc]      = vf0;
        *(float4*)&Vs[vr + 32][vc] = vf1;
        if (t + 1 < 16) {
#pragma unroll
            for (int i = 0; i < 4; ++i)
                pf[i] = *(const float4*)(abase + (t + 1) * 64 + i * 4);
            vf0 = *(const float4*)(vbase + (t + 1) * 64);
            vf1 = *(const float4*)(vbase + (long)32 * Tt + (t + 1) * 64);
        }
        __syncthreads();
#pragma unroll
        for (int kk = 0; kk < 64; kk += 32) {
            bf16x8 a0 = *(bf16x8*)&Ps[wq + ml][kk + q8];
            bf16x8 a1 = *(bf16x8*)&Ps[wq + 16 + ml][kk + q8];
            bf16x8 b0 = *(bf16x8*)&Vs[wd + ml][kk + q8];
            bf16x8 b1 = *(bf16x8*)&Vs[wd + 16 + ml][kk + q8];
            acc[0][0] = __builtin_amdgcn_mfma_f32_16x16x32_bf16(a0, b0, acc[0][0], 0, 0, 0);
            acc[0][1] = __builtin_amdgcn_mfma_f32_16x16x32_bf16(a0, b1, acc[0][1], 0, 0, 0);
            acc[1][0] = __builtin_amdgcn_mfma_f32_16x16x32_bf16(a1, b0, acc[1][0], 0, 0, 0);
            acc[1][1] = __builtin_amdgcn_mfma_f32_16x16x32_bf16(a1, b1, acc[1][1], 0, 0, 0);
        }
        __syncthreads();
    }

#pragma unroll
    for (int i = 0; i < 2; ++i)
#pragma unroll
        for (int j = 0; j < 2; ++j)
#pragma unroll
            for (int r = 0; r < 4; ++r)
                o1p[((long)(b * Tt + qt * 64 + wq + i * 16 + q4 + r)) * HSc + wd + j * 16 + ml] =
                    acc[i][j][r];
}

// ---------------------------------------------------------------------------
extern "C" void kernel_launch(void* const* d_in, const int* in_sizes, int n_in,
                              void* d_out, int out_size, void* d_ws, size_t ws_size,
                              hipStream_t stream)
{
    const float* x  = (const float*)d_in[0];
    const float* Wq = (const float*)d_in[1];
    const float* bq = (const float*)d_in[2];
    const float* Wk = (const float*)d_in[3];
    const float* bk = (const float*)d_in[4];
    const float* Wv = (const float*)d_in[5];
    const float* bv = (const float*)d_in[6];
    const float* Wo = (const float*)d_in[7];
    const float* bo = (const float*)d_in[8];

    float* out  = (float*)d_out;                    // B*T*HID
    float* attn = out + (long)BTc * HIDc;           // B*T*T

    // workspace: xb | Wqt | Wkt | Wvt | qb | kb | v | linv | o1a  (~59 MB)
    // dead-buffer reuse: vbT overlays Wqt (free after Q proj);
    //                    o1b overlays Wkt (free after K proj; 2 MB exactly).
    unsigned short* xb  = (unsigned short*)d_ws;
    unsigned short* Wqt = xb  + (long)BTc * HIDc;
    unsigned short* Wkt = Wqt + (long)HIDc * HIDc;
    unsigned short* Wvt = Wkt + (long)HIDc * HIDc;
    unsigned short* qb  = Wvt + (long)HSc * HIDc;
    unsigned short* kb  = qb  + (long)BTc * HIDc;
    float* v    = (float*)(kb + (long)BTc * HIDc);
    float* linv = v    + (long)BTc * HSc;
    float* o1a  = linv + (long)Bc * NHc * Tt;
    unsigned short* vbT = Wqt;          // B*HS*T bf16 = 1 MB  (<= 2 MB slot)
    float* o1b = (float*)Wkt;           // B*T*HS fp32 = 2 MB  (== 2 MB slot)

    dim3 blk(256);

    // prep: casts + weight transposes + V-bias init (ws is poisoned)
    cast_bf16<<<dim3((BTc * HIDc) / 1024), blk, 0, stream>>>(x, xb, (long)BTc * HIDc);
    transpose_cast<<<dim3(32, 32), blk, 0, stream>>>(Wq, Wqt, HIDc, HIDc);
    transpose_cast<<<dim3(32, 32), blk, 0, stream>>>(Wk, Wkt, HIDc, HIDc);
    transpose_cast<<<dim3(32, 2),  blk, 0, stream>>>(Wv, Wvt, HIDc, HSc);
    init_bias64<<<dim3((BTc * HSc) / 256), blk, 0, stream>>>(v, bv, (long)BTc * HSc);

    // Q/K projections (bf16 MFMA). Q pre-scaled by 0.125*log2(e) for exp2.
    gemm_bt_bf16<<<dim3(HIDc / 128, BTc / 128), blk, 0, stream>>>(xb, Wqt, bq, qb, BTc, HIDc, HIDc, QSCALE);
    gemm_bt_bf16<<<dim3(HIDc / 128, BTc / 128), blk, 0, stream>>>(xb, Wkt, bk, kb, BTc, HIDc, HIDc, 1.0f);

    // V projection: bf16 MFMA split-K (atomics into fp32 v, bias-preinit'd)
    gemm_v_bf16<<<dim3(BTc / 128, HIDc / 256), blk, 0, stream>>>(xb, Wvt, v);

    // v (B,T,64) fp32 -> vT (B,64,T) bf16 for the PV GEMM's B-operand.
    for (int bi = 0; bi < Bc; ++bi)
        transpose_cast<<<dim3(Tt / 32, HSc / 32), blk, 0, stream>>>(
            v + (long)bi * Tt * HSc, vbT + (long)bi * HSc * Tt, Tt, HSc);

    // pass 1: softmax denominators (128 q-rows per block, prefetched K tiles)
    attn_denom<<<dim3(Tt / 128, NHc, Bc), blk, 0, stream>>>(qb, kb, linv);

    // pass 2: head-averaged attn tile (LDS-bounced wide stores)
    attn_avg_w<<<dim3(Tt / 128, Tt / 64, Bc), blk, 0, stream>>>(qb, kb, linv, attn);

    // PV from the L3-hot attn: o1a/o1b partials, no atomics
    gemm_pv<<<dim3(Tt / 64, 2, Bc), blk, 0, stream>>>(attn, vbT, o1a, o1b);

    // out = (o1a + o1b) @ Wo + bo
    gemm_f32<<<dim3(HIDc / 64, BTc / 64), blk, 0, stream>>>(o1a, o1b, Wo, bo, out, BTc, HIDc, HSc);
}